// Round 5
// baseline (307.393 us; speedup 1.0000x reference)
//
#include <hip/hip_runtime.h>

#define NTOK 32768

typedef __attribute__((ext_vector_type(8))) short  bf16x8;
typedef __attribute__((ext_vector_type(8))) unsigned short u16x8;
typedef __attribute__((ext_vector_type(4))) float  f32x4;

__device__ __forceinline__ unsigned short f32_to_bf16(float f) {
    unsigned int u = __float_as_uint(f);
    u += 0x7FFFu + ((u >> 16) & 1u);          // round-to-nearest-even
    return (unsigned short)(u >> 16);
}
__device__ __forceinline__ float bf16_to_f32(unsigned short h) {
    return __uint_as_float(((unsigned int)h) << 16);
}

// ---------------------------------------------------------------------------
// B-stationary MFMA GEMM: C[M,NTOK] = A[M,256] * B[256,NTOK].
// One block per 64-col strip (x) per batch (y): B strip [256k][64n] fetched
// from HBM exactly once, stored transposed+XOR-swizzled bf16 in 32 KB LDS.
// 4 blocks/CU (launch_bounds(256,4)) for latency hiding; grid = 1024 blocks.
// Waves: 4 x (32 rows x 64 cols); per chunk of 128 rows, wave w owns rows
// w*32..w*32+31 -> acc[2][4] (32 VGPRs). A fragments gathered directly from
// global (A is tiny, L2-resident); no barriers inside the K-loop.
// QSOFT: chunks 0,1 are q rows; each wave's 32 rows = exactly one head ->
// softmax across mt/r in-lane + quad reduction via shfl_xor 16/32.
// ---------------------------------------------------------------------------
template <typename BT, typename CT, int MCHUNKS, bool QSOFT>
__global__ __launch_bounds__(256, 4) void gemm_bstat(
    const unsigned short* __restrict__ A, const BT* __restrict__ B,
    CT* __restrict__ C, long sA, long sB, long sC)
{
    const int bz = blockIdx.y;
    A += (long)bz * sA; B += (long)bz * sB; C += (long)bz * sC;
    const int col0 = blockIdx.x * 64;

    __shared__ unsigned short Bs[64 * 256];   // 32 KB

    const int t = threadIdx.x;
    const int wave = t >> 6, lane = t & 63;
    const int m16 = lane & 15, quad = lane >> 4;

    // ---- stage B strip once: [256k][64n] -> Bs[n][256k] bf16, XOR-swizzled
    {
        const int n = t & 63;                 // wave covers 64 consecutive n
        const int kg0 = (t >> 6) * 8;         // each wave: 8 granules of k
        const int key = n & 7;
        const BT* bcol = B + col0 + n;
        #pragma unroll
        for (int g = 0; g < 8; ++g) {
            const int kg = kg0 + g;           // 16B granule index along k (0..31)
            unsigned short tmp[8];
            #pragma unroll
            for (int i = 0; i < 8; ++i) {
                BT v = bcol[(size_t)(kg * 8 + i) * NTOK];
                if constexpr (sizeof(BT) == 4) tmp[i] = f32_to_bf16((float)v);
                else                           tmp[i] = (unsigned short)v;
            }
            *(u16x8*)&Bs[n * 256 + ((kg ^ key) * 8)] = *(const u16x8*)tmp;
        }
    }
    __syncthreads();   // the only barrier

    const int swk = m16 & 7;

    for (int mc = 0; mc < MCHUNKS; ++mc) {
        const int m0 = mc * 128;
        f32x4 acc[2][4] = {};

        const unsigned short* Abase =
            A + (size_t)(m0 + wave * 32 + m16) * 256 + quad * 8;

        #pragma unroll
        for (int kk = 0; kk < 8; ++kk) {
            bf16x8 bf[4];
            #pragma unroll
            for (int nt = 0; nt < 4; ++nt) {
                const int col = nt * 16 + m16;
                bf[nt] = *(const bf16x8*)&Bs[col * 256 + (((kk * 4 + quad) ^ swk) * 8)];
            }
            #pragma unroll
            for (int mt = 0; mt < 2; ++mt) {
                const bf16x8 af = *(const bf16x8*)&Abase[(size_t)mt * 16 * 256 + kk * 32];
                #pragma unroll
                for (int nt = 0; nt < 4; ++nt)
                    acc[mt][nt] = __builtin_amdgcn_mfma_f32_16x16x32_bf16(
                        af, bf[nt], acc[mt][nt], 0, 0, 0);
            }
        }

        // ---- fused q softmax: wave's 32 rows = one head
        if (QSOFT && m0 < 256) {
            #pragma unroll
            for (int nt = 0; nt < 4; ++nt) {
                float mx = -1e30f;
                #pragma unroll
                for (int mt = 0; mt < 2; ++mt)
                    #pragma unroll
                    for (int r = 0; r < 4; ++r)
                        mx = fmaxf(mx, acc[mt][nt][r]);
                mx = fmaxf(mx, __shfl_xor(mx, 16, 64));
                mx = fmaxf(mx, __shfl_xor(mx, 32, 64));
                float s = 0.f;
                #pragma unroll
                for (int mt = 0; mt < 2; ++mt)
                    #pragma unroll
                    for (int r = 0; r < 4; ++r) {
                        const float e = __expf(acc[mt][nt][r] - mx);
                        acc[mt][nt][r] = e;
                        s += e;
                    }
                s += __shfl_xor(s, 16, 64);
                s += __shfl_xor(s, 32, 64);
                const float inv = 1.0f / s;
                #pragma unroll
                for (int mt = 0; mt < 2; ++mt)
                    #pragma unroll
                    for (int r = 0; r < 4; ++r)
                        acc[mt][nt][r] *= inv;
            }
        }

        // ---- store: D[row][col], col = lane&15, row = quad*4 + r
        #pragma unroll
        for (int mt = 0; mt < 2; ++mt) {
            #pragma unroll
            for (int nt = 0; nt < 4; ++nt) {
                #pragma unroll
                for (int r = 0; r < 4; ++r) {
                    const int row = m0 + wave * 32 + mt * 16 + quad * 4 + r;
                    const int col = col0 + nt * 16 + m16;
                    if constexpr (sizeof(CT) == 4)
                        C[(size_t)row * NTOK + col] = acc[mt][nt][r];
                    else
                        C[(size_t)row * NTOK + col] = f32_to_bf16(acc[mt][nt][r]);
                }
            }
        }
    }
}

// ---------------------------------------------------------------------------
// fp32 -> bf16 cast (vectorized)
// ---------------------------------------------------------------------------
__global__ __launch_bounds__(256) void cast_bf16_kernel(
    const float* __restrict__ src, unsigned short* __restrict__ dst, int n4)
{
    const int i = blockIdx.x * 256 + threadIdx.x;
    if (i < n4) {
        float4 v = ((const float4*)src)[i];
        ushort4 o;
        o.x = f32_to_bf16(v.x); o.y = f32_to_bf16(v.y);
        o.z = f32_to_bf16(v.z); o.w = f32_to_bf16(v.w);
        ((ushort4*)dst)[i] = o;
    }
}

// ---------------------------------------------------------------------------
// context num[b,h,d,e] = sum_n exp(k[n,d]) * v[n,e]; den = sum_n exp(k[n,d]).
// No max subtraction (k is small-range; softmax shift-invariant).
// ---------------------------------------------------------------------------
#define CTILE 128
__global__ __launch_bounds__(256) void ctx_kernel(
    const unsigned short* __restrict__ qkv,
    float* __restrict__ num, float* __restrict__ den, int tokens_per_block)
{
    const int chunk = blockIdx.x, h = blockIdx.y, b = blockIdx.z;
    const int n0 = chunk * tokens_per_block;
    const unsigned short* kbase = qkv + ((long)b * 768 + 256 + h * 32) * NTOK;
    const unsigned short* vbase = qkv + ((long)b * 768 + 512 + h * 32) * NTOK;

    __shared__ float ks[32][CTILE + 2];   // [d][tok]
    __shared__ float vs[CTILE][36];       // [tok][e], pitch 36 keeps 16B align

    const int t = threadIdx.x;
    const int d = t >> 3, eg = t & 7;     // compute mapping
    const int lrow = t >> 3, lf = t & 7;  // load mapping

    float acc[4] = {0.f, 0.f, 0.f, 0.f};
    float dsum = 0.f;

    for (int tile = 0; tile < tokens_per_block; tile += CTILE) {
        #pragma unroll 4
        for (int jj = 0; jj < 16; ++jj) {
            const int tok = lf + 8 * jj;
            const long g = (long)lrow * NTOK + n0 + tile + tok;
            ks[lrow][tok] = __expf(bf16_to_f32(kbase[g]));
            vs[tok][lrow] = bf16_to_f32(vbase[g]);
        }
        __syncthreads();
        for (int tok = 0; tok < CTILE; ++tok) {
            const float ek = ks[d][tok];
            dsum += ek;
            const float4 vv = *(const float4*)&vs[tok][eg * 4];
            acc[0] += ek * vv.x; acc[1] += ek * vv.y;
            acc[2] += ek * vv.z; acc[3] += ek * vv.w;
        }
        __syncthreads();
    }
    float* nrow = num + (((long)(b * 8 + h) * 32 + d) * 32);
    #pragma unroll
    for (int i = 0; i < 4; ++i) atomicAdd(&nrow[eg * 4 + i], acc[i]);
    if (eg == 0) atomicAdd(&den[b * 256 + h * 32 + d], dsum);
}

// ---------------------------------------------------------------------------
// W2[b][o][h*32+d] = (sum_e w_out[o,h*32+e] * num[b,h,d,e]) / den[b,h*32+d]
// ---------------------------------------------------------------------------
__global__ __launch_bounds__(256) void combine_kernel(
    const float* __restrict__ w_out, const float* __restrict__ num,
    const float* __restrict__ den, unsigned short* __restrict__ W2)
{
    const int tid = blockIdx.x * 256 + threadIdx.x;   // 2*256*256 total
    const int b = tid >> 16;
    const int rem = tid & 65535;
    const int o = rem >> 8;
    const int i = rem & 255;
    const int h = i >> 5, d = i & 31;
    const float* wrow = w_out + o * 256 + h * 32;
    const float* nrow = num + (((long)(b * 8 + h) * 32 + d) << 5);
    float s = 0.f;
    #pragma unroll
    for (int e = 0; e < 32; ++e) s += wrow[e] * nrow[e];
    W2[tid] = f32_to_bf16(s / den[b * 256 + h * 32 + d]);
}

// ---------------------------------------------------------------------------
extern "C" void kernel_launch(void* const* d_in, const int* in_sizes, int n_in,
                              void* d_out, int out_size, void* d_ws, size_t ws_size,
                              hipStream_t stream)
{
    const float* x     = (const float*)d_in[0];   // [2,256,32768]
    const float* w_qkv = (const float*)d_in[1];   // [768,256]
    const float* w_out = (const float*)d_in[2];   // [256,256]
    float* out = (float*)d_out;                   // [2,256,32768]

    // workspace layout
    unsigned short* qkv_bf = (unsigned short*)d_ws;           // 2*768*32768 bf16
    const long qkv_elems = 2L * 768 * NTOK;
    unsigned short* wqkv_bf = qkv_bf + qkv_elems;             // 768*256 bf16
    unsigned short* W2 = wqkv_bf + 768 * 256;                 // 2*256*256 bf16
    float* num  = (float*)(W2 + 2 * 256 * 256);               // 16384
    float* den  = num + 16384;                                // 512

    hipMemsetAsync(num, 0, (16384 + 512) * sizeof(float), stream);

    // 0) cast w_qkv to bf16
    cast_bf16_kernel<<<192, 256, 0, stream>>>(w_qkv, wqkv_bf, 768 * 256 / 4);

    // 1) qkv = w_qkv @ x, q rows softmax'd in-epilogue; x read once
    gemm_bstat<float, unsigned short, 6, true><<<dim3(512, 2), 256, 0, stream>>>(
        wqkv_bf, x, qkv_bf, 0L, 256L * NTOK, 768L * NTOK);

    // 2) context num/den
    ctx_kernel<<<dim3(64, 8, 2), 256, 0, stream>>>(qkv_bf, num, den, NTOK / 64);

    // 3) W2 = fold(w_out, context) -> bf16
    combine_kernel<<<512, 256, 0, stream>>>(w_out, num, den, W2);

    // 4) out(fp32) = W2(bf16) @ q_soft(bf16); q_soft read once
    gemm_bstat<unsigned short, float, 2, false><<<dim3(512, 2), 256, 0, stream>>>(
        W2, qkv_bf, out, 65536L, 768L * NTOK, 256L * NTOK);
}

// Round 6
// 303.702 us; speedup vs baseline: 1.0122x; 1.0122x over previous
//
#include <hip/hip_runtime.h>

#define NTOK 32768

typedef __attribute__((ext_vector_type(8))) short  bf16x8;
typedef __attribute__((ext_vector_type(8))) unsigned short u16x8;
typedef __attribute__((ext_vector_type(4))) float  f32x4;

__device__ __forceinline__ unsigned short f32_to_bf16(float f) {
    unsigned int u = __float_as_uint(f);
    u += 0x7FFFu + ((u >> 16) & 1u);          // round-to-nearest-even
    return (unsigned short)(u >> 16);
}
__device__ __forceinline__ float bf16_to_f32(unsigned short h) {
    return __uint_as_float(((unsigned int)h) << 16);
}

// ---------------------------------------------------------------------------
// B-stationary MFMA GEMM: C[M,NTOK] = A[M,256] * B[256,NTOK].
// One block per 128-col strip (x) per batch (y): B strip [256k][128n] fetched
// from HBM exactly once, stored transposed+XOR-swizzled bf16 in 64 KB LDS.
// (128-col strips keep per-row HBM segments >= 256 B -> no partial-line
//  RMW/write amplification; 64-col strips measurably poison FETCH/WRITE.)
// 512 threads = 8 waves (4 row-tiles x 2 col-halves), launch_bounds(512,4)
// -> 2 blocks/CU, 16 waves/CU for latency hiding. Wave = 32 rows x 64 cols,
// acc[2][4] = 32 VGPRs. A fragments gathered directly from global (A tiny,
// L2-resident); no barriers inside the K-loop.
// QSOFT: chunks 0,1 are q rows; each wave's 32 rows = exactly one head ->
// softmax across mt/r in-lane + quad reduction via shfl_xor 16/32.
// ---------------------------------------------------------------------------
template <typename BT, typename CT, int MCHUNKS, bool QSOFT>
__global__ __launch_bounds__(512, 4) void gemm_bstat(
    const unsigned short* __restrict__ A, const BT* __restrict__ B,
    CT* __restrict__ C, long sA, long sB, long sC)
{
    const int bz = blockIdx.y;
    A += (long)bz * sA; B += (long)bz * sB; C += (long)bz * sC;
    const int col0 = blockIdx.x * 128;

    __shared__ unsigned short Bs[128 * 256];   // 64 KB

    const int t = threadIdx.x;
    const int wave = t >> 6, lane = t & 63;
    const int wm = wave >> 1, wn = wave & 1;
    const int m16 = lane & 15, quad = lane >> 4;

    // ---- stage B strip once: [256k][128n] -> Bs[n][256k] bf16, XOR-swizzled
    {
        const int n = t & 127;                // each wave: 64 consecutive n
        const int kg0 = (t >> 7) * 8;         // 4 thread-groups x 8 granules
        const int key = n & 7;
        const BT* bcol = B + col0 + n;
        #pragma unroll
        for (int g = 0; g < 8; ++g) {
            const int kg = kg0 + g;           // 16B granule index along k (0..31)
            unsigned short tmp[8];
            #pragma unroll
            for (int i = 0; i < 8; ++i) {
                BT v = bcol[(size_t)(kg * 8 + i) * NTOK];
                if constexpr (sizeof(BT) == 4) tmp[i] = f32_to_bf16((float)v);
                else                           tmp[i] = (unsigned short)v;
            }
            *(u16x8*)&Bs[n * 256 + ((kg ^ key) * 8)] = *(const u16x8*)tmp;
        }
    }
    __syncthreads();   // the only barrier

    const int swk = m16 & 7;

    for (int mc = 0; mc < MCHUNKS; ++mc) {
        const int m0 = mc * 128;
        f32x4 acc[2][4] = {};

        const unsigned short* Abase =
            A + (size_t)(m0 + wm * 32 + m16) * 256 + quad * 8;

        #pragma unroll
        for (int kk = 0; kk < 8; ++kk) {
            bf16x8 bf[4];
            #pragma unroll
            for (int nt = 0; nt < 4; ++nt) {
                const int col = wn * 64 + nt * 16 + m16;
                bf[nt] = *(const bf16x8*)&Bs[col * 256 + (((kk * 4 + quad) ^ swk) * 8)];
            }
            #pragma unroll
            for (int mt = 0; mt < 2; ++mt) {
                const bf16x8 af = *(const bf16x8*)&Abase[(size_t)mt * 16 * 256 + kk * 32];
                #pragma unroll
                for (int nt = 0; nt < 4; ++nt)
                    acc[mt][nt] = __builtin_amdgcn_mfma_f32_16x16x32_bf16(
                        af, bf[nt], acc[mt][nt], 0, 0, 0);
            }
        }

        // ---- fused q softmax: wave's 32 rows = one head
        if (QSOFT && m0 < 256) {
            #pragma unroll
            for (int nt = 0; nt < 4; ++nt) {
                float mx = -1e30f;
                #pragma unroll
                for (int mt = 0; mt < 2; ++mt)
                    #pragma unroll
                    for (int r = 0; r < 4; ++r)
                        mx = fmaxf(mx, acc[mt][nt][r]);
                mx = fmaxf(mx, __shfl_xor(mx, 16, 64));
                mx = fmaxf(mx, __shfl_xor(mx, 32, 64));
                float s = 0.f;
                #pragma unroll
                for (int mt = 0; mt < 2; ++mt)
                    #pragma unroll
                    for (int r = 0; r < 4; ++r) {
                        const float e = __expf(acc[mt][nt][r] - mx);
                        acc[mt][nt][r] = e;
                        s += e;
                    }
                s += __shfl_xor(s, 16, 64);
                s += __shfl_xor(s, 32, 64);
                const float inv = 1.0f / s;
                #pragma unroll
                for (int mt = 0; mt < 2; ++mt)
                    #pragma unroll
                    for (int r = 0; r < 4; ++r)
                        acc[mt][nt][r] *= inv;
            }
        }

        // ---- store: D[row][col], col = lane&15, row = quad*4 + r
        #pragma unroll
        for (int mt = 0; mt < 2; ++mt) {
            #pragma unroll
            for (int nt = 0; nt < 4; ++nt) {
                #pragma unroll
                for (int r = 0; r < 4; ++r) {
                    const int row = m0 + wm * 32 + mt * 16 + quad * 4 + r;
                    const int col = col0 + wn * 64 + nt * 16 + m16;
                    if constexpr (sizeof(CT) == 4)
                        C[(size_t)row * NTOK + col] = acc[mt][nt][r];
                    else
                        C[(size_t)row * NTOK + col] = f32_to_bf16(acc[mt][nt][r]);
                }
            }
        }
    }
}

// ---------------------------------------------------------------------------
// fp32 -> bf16 cast (vectorized)
// ---------------------------------------------------------------------------
__global__ __launch_bounds__(256) void cast_bf16_kernel(
    const float* __restrict__ src, unsigned short* __restrict__ dst, int n4)
{
    const int i = blockIdx.x * 256 + threadIdx.x;
    if (i < n4) {
        float4 v = ((const float4*)src)[i];
        ushort4 o;
        o.x = f32_to_bf16(v.x); o.y = f32_to_bf16(v.y);
        o.z = f32_to_bf16(v.z); o.w = f32_to_bf16(v.w);
        ((ushort4*)dst)[i] = o;
    }
}

// ---------------------------------------------------------------------------
// context num[b,h,d,e] = sum_n exp(k[n,d]) * v[n,e]; den = sum_n exp(k[n,d]).
// No max subtraction (k is small-range; softmax shift-invariant).
// ---------------------------------------------------------------------------
#define CTILE 128
__global__ __launch_bounds__(256) void ctx_kernel(
    const unsigned short* __restrict__ qkv,
    float* __restrict__ num, float* __restrict__ den, int tokens_per_block)
{
    const int chunk = blockIdx.x, h = blockIdx.y, b = blockIdx.z;
    const int n0 = chunk * tokens_per_block;
    const unsigned short* kbase = qkv + ((long)b * 768 + 256 + h * 32) * NTOK;
    const unsigned short* vbase = qkv + ((long)b * 768 + 512 + h * 32) * NTOK;

    __shared__ float ks[32][CTILE + 2];   // [d][tok]
    __shared__ float vs[CTILE][36];       // [tok][e], pitch 36 keeps 16B align

    const int t = threadIdx.x;
    const int d = t >> 3, eg = t & 7;     // compute mapping
    const int lrow = t >> 3, lf = t & 7;  // load mapping

    float acc[4] = {0.f, 0.f, 0.f, 0.f};
    float dsum = 0.f;

    for (int tile = 0; tile < tokens_per_block; tile += CTILE) {
        #pragma unroll 4
        for (int jj = 0; jj < 16; ++jj) {
            const int tok = lf + 8 * jj;
            const long g = (long)lrow * NTOK + n0 + tile + tok;
            ks[lrow][tok] = __expf(bf16_to_f32(kbase[g]));
            vs[tok][lrow] = bf16_to_f32(vbase[g]);
        }
        __syncthreads();
        for (int tok = 0; tok < CTILE; ++tok) {
            const float ek = ks[d][tok];
            dsum += ek;
            const float4 vv = *(const float4*)&vs[tok][eg * 4];
            acc[0] += ek * vv.x; acc[1] += ek * vv.y;
            acc[2] += ek * vv.z; acc[3] += ek * vv.w;
        }
        __syncthreads();
    }
    float* nrow = num + (((long)(b * 8 + h) * 32 + d) * 32);
    #pragma unroll
    for (int i = 0; i < 4; ++i) atomicAdd(&nrow[eg * 4 + i], acc[i]);
    if (eg == 0) atomicAdd(&den[b * 256 + h * 32 + d], dsum);
}

// ---------------------------------------------------------------------------
// W2[b][o][h*32+d] = (sum_e w_out[o,h*32+e] * num[b,h,d,e]) / den[b,h*32+d]
// ---------------------------------------------------------------------------
__global__ __launch_bounds__(256) void combine_kernel(
    const float* __restrict__ w_out, const float* __restrict__ num,
    const float* __restrict__ den, unsigned short* __restrict__ W2)
{
    const int tid = blockIdx.x * 256 + threadIdx.x;   // 2*256*256 total
    const int b = tid >> 16;
    const int rem = tid & 65535;
    const int o = rem >> 8;
    const int i = rem & 255;
    const int h = i >> 5, d = i & 31;
    const float* wrow = w_out + o * 256 + h * 32;
    const float* nrow = num + (((long)(b * 8 + h) * 32 + d) << 5);
    float s = 0.f;
    #pragma unroll
    for (int e = 0; e < 32; ++e) s += wrow[e] * nrow[e];
    W2[tid] = f32_to_bf16(s / den[b * 256 + h * 32 + d]);
}

// ---------------------------------------------------------------------------
extern "C" void kernel_launch(void* const* d_in, const int* in_sizes, int n_in,
                              void* d_out, int out_size, void* d_ws, size_t ws_size,
                              hipStream_t stream)
{
    const float* x     = (const float*)d_in[0];   // [2,256,32768]
    const float* w_qkv = (const float*)d_in[1];   // [768,256]
    const float* w_out = (const float*)d_in[2];   // [256,256]
    float* out = (float*)d_out;                   // [2,256,32768]

    // workspace layout
    unsigned short* qkv_bf = (unsigned short*)d_ws;           // 2*768*32768 bf16
    const long qkv_elems = 2L * 768 * NTOK;
    unsigned short* wqkv_bf = qkv_bf + qkv_elems;             // 768*256 bf16
    unsigned short* W2 = wqkv_bf + 768 * 256;                 // 2*256*256 bf16
    float* num  = (float*)(W2 + 2 * 256 * 256);               // 16384
    float* den  = num + 16384;                                // 512

    hipMemsetAsync(num, 0, (16384 + 512) * sizeof(float), stream);

    // 0) cast w_qkv to bf16
    cast_bf16_kernel<<<192, 256, 0, stream>>>(w_qkv, wqkv_bf, 768 * 256 / 4);

    // 1) qkv = w_qkv @ x, q rows softmax'd in-epilogue; x read once
    gemm_bstat<float, unsigned short, 6, true><<<dim3(256, 2), 512, 0, stream>>>(
        wqkv_bf, x, qkv_bf, 0L, 256L * NTOK, 768L * NTOK);

    // 2) context num/den
    ctx_kernel<<<dim3(64, 8, 2), 256, 0, stream>>>(qkv_bf, num, den, NTOK / 64);

    // 3) W2 = fold(w_out, context) -> bf16
    combine_kernel<<<512, 256, 0, stream>>>(w_out, num, den, W2);

    // 4) out(fp32) = W2(bf16) @ q_soft(bf16); q_soft read once
    gemm_bstat<unsigned short, float, 2, false><<<dim3(256, 2), 512, 0, stream>>>(
        W2, qkv_bf, out, 65536L, 768L * NTOK, 256L * NTOK);
}